// Round 22
// baseline (62.081 us; speedup 1.0000x reference)
//
#include <hip/hip_runtime.h>

#define NJ     62
#define NV     14522
#define NCORE  28
#define KPAD   256    // 62*4 = 248 padded to 256 (512 B per row)
#define OUTF   (NV * 3)        // 43566
#define MT     908             // m-tiles of 16 rows
#define WHBLK  227             // ceil(NV*4/256) blocks for WH build

typedef __attribute__((ext_vector_type(8))) short short8v;
typedef __attribute__((ext_vector_type(4))) short short4v;
typedef __attribute__((ext_vector_type(4))) float floatx4;
typedef __attribute__((ext_vector_type(2))) float floatx2;

#define AS1(p) ((const __attribute__((address_space(1))) void*)(p))
#define AS3(p) ((__attribute__((address_space(3))) void*)(p))

#define SCHED0() __builtin_amdgcn_sched_barrier(0)
#define WAITVM0() do { SCHED0(); asm volatile("s_waitcnt vmcnt(0)" ::: "memory"); SCHED0(); } while (0)

static __device__ inline short f2bf(float x) {
    unsigned u = __float_as_uint(x);
    unsigned r = (u + 0x7fffu + ((u >> 16) & 1u)) >> 16;
    return (short)r;
}

// XOR swizzle over 512B rows: involution; global SOURCE at staging and LDS
// read addresses (both-sides rule). Proven in r6.
static __device__ inline unsigned swz(unsigned off) {
    return off ^ (((off >> 9) & 7u) << 4);
}

// ---------------------------------------------------------------------------
// Kernel 1 (fused prep):
//  blocks [0,64):  FK, 4 batches/block (1 per wave). Writes Jout (fp32) and
//    Bt (bf16) in the PERMUTED K layout:
//      joint j, comp m at q = 32*((j&15)>>1) + 8*(j>>4) + 4*(j&1) + m
//  blocks [64,64+WHBLK): build WH[v][q] = w[v, j(q)] * h[m], h=(x,y,z,1),
//    same permuted layout -> gemm's A-frag is one contiguous 16B load/k8.
// ---------------------------------------------------------------------------
__global__ __launch_bounds__(256) void prep_kernel(
    const float* __restrict__ thetas, const float* __restrict__ blc,
    const float* __restrict__ cbl, const float* __restrict__ trans,
    const float* __restrict__ scale, const float* __restrict__ tpose,
    const int* __restrict__ parents, const int* __restrict__ mapper,
    const float* __restrict__ W, const float* __restrict__ vt,
    short* __restrict__ Bt, short* __restrict__ WH,
    float* __restrict__ Jout)
{
    __shared__ float Asm[4][NJ][12];
    __shared__ float Gsm[4][NJ][12];

    if (blockIdx.x >= 64) {
        // ---- WH build role: thread id -> (v, lk)
        const int id = (blockIdx.x - 64) * 256 + threadIdx.x;
        const int v  = id >> 2;
        const int lk = id & 3;
        if (v >= NV) return;
        float wj[16];
        #pragma unroll
        for (int e = 0; e < 16; ++e) {
            const int j = lk * 16 + e;
            wj[e] = (j < NJ) ? W[(size_t)v * NJ + j] : 0.f;
        }
        const float hx = vt[v * 3 + 0], hy = vt[v * 3 + 1], hz = vt[v * 3 + 2];
        short* dst = WH + (size_t)v * KPAD + lk * 8;
        #pragma unroll
        for (int k8 = 0; k8 < 8; ++k8) {
            const float w0 = wj[2 * k8], w1 = wj[2 * k8 + 1];
            short8v o;
            o[0] = f2bf(w0 * hx); o[1] = f2bf(w0 * hy);
            o[2] = f2bf(w0 * hz); o[3] = f2bf(w0);
            o[4] = f2bf(w1 * hx); o[5] = f2bf(w1 * hy);
            o[6] = f2bf(w1 * hz); o[7] = f2bf(w1);
            *(short8v*)(dst + k8 * 32) = o;
        }
        return;
    }

    // ---- FK role (r17-identical)
    const int w = threadIdx.x >> 6;
    const int b = blockIdx.x * 4 + w;
    const int k = threadIdx.x & 63;
    int p = 0;

    if (k < NJ) {
        p = parents[k];
        const float tz = thetas[(b * NJ + k) * 3 + 0];
        const float ty = thetas[(b * NJ + k) * 3 + 1];
        const float tx = thetas[(b * NJ + k) * 3 + 2];
        const float cx = cosf(tx), sx = sinf(tx);
        const float cy = cosf(ty), sy = sinf(ty);
        const float cz = cosf(tz), sz = sinf(tz);
        const float r00 = cz * cy;
        const float r01 = cz * sy * sx - sz * cx;
        const float r02 = sz * sx + cz * sy * cx;
        const float r10 = sz * cy;
        const float r11 = cz * cx + sz * sy * sx;
        const float r12 = sz * sy * cx - cz * sx;
        const float r20 = -sy;
        const float r21 = cy * sx;
        const float r22 = cy * cx;

        float f;
        const int m = mapper[k];
        if (k == 0)        f = 1.0f;
        else if (k == 1)   f = cbl[b];
        else if (m < 0)    f = 1.0f;
        else               f = 2.0f / (1.0f + expf(-blc[b * NCORE + m] * 0.2f));

        float ox, oy, oz;
        if (k == 0) {
            ox = tpose[0]; oy = tpose[1]; oz = tpose[2];
        } else {
            ox = (tpose[k * 3 + 0] - tpose[p * 3 + 0]) * f;
            oy = (tpose[k * 3 + 1] - tpose[p * 3 + 1]) * f;
            oz = (tpose[k * 3 + 2] - tpose[p * 3 + 2]) * f;
        }
        Asm[w][k][0] = r00; Asm[w][k][1] = r01; Asm[w][k][2]  = r02; Asm[w][k][3]  = ox;
        Asm[w][k][4] = r10; Asm[w][k][5] = r11; Asm[w][k][6]  = r12; Asm[w][k][7]  = oy;
        Asm[w][k][8] = r20; Asm[w][k][9] = r21; Asm[w][k][10] = r22; Asm[w][k][11] = oz;
    }
    __syncthreads();

    if (k == 0) {
        #pragma unroll
        for (int j = 0; j < 12; ++j) Gsm[w][0][j] = Asm[w][0][j];
    }
    __syncthreads();

    const int depth = (k < NJ) ? (31 - __clz((unsigned)(k + 1))) : 99;
    for (int d = 1; d <= 5; ++d) {
        if (depth == d) {
            float gp[12], a[12], g[12];
            #pragma unroll
            for (int j = 0; j < 12; ++j) { gp[j] = Gsm[w][p][j]; a[j] = Asm[w][k][j]; }
            #pragma unroll
            for (int i = 0; i < 3; ++i) {
                #pragma unroll
                for (int j = 0; j < 4; ++j) {
                    float s = (j == 3) ? gp[i * 4 + 3] : 0.0f;
                    s = fmaf(gp[i * 4 + 0], a[0 * 4 + j], s);
                    s = fmaf(gp[i * 4 + 1], a[1 * 4 + j], s);
                    s = fmaf(gp[i * 4 + 2], a[2 * 4 + j], s);
                    g[i * 4 + j] = s;
                }
            }
            #pragma unroll
            for (int j = 0; j < 12; ++j) Gsm[w][k][j] = g[j];
        }
        __syncthreads();
    }

    if (k < NJ) {
        float g[12];
        #pragma unroll
        for (int j = 0; j < 12; ++j) g[j] = Gsm[w][k][j];
        const float jx = tpose[k * 3 + 0];
        const float jy = tpose[k * 3 + 1];
        const float jz = tpose[k * 3 + 2];
        const float s  = scale[b];
        Jout[(b * NJ + k) * 3 + 0] = fmaf(g[3],  s, trans[b * 3 + 0]);
        Jout[(b * NJ + k) * 3 + 1] = fmaf(g[7],  s, trans[b * 3 + 1]);
        Jout[(b * NJ + k) * 3 + 2] = fmaf(g[11], s, trans[b * 3 + 2]);
        float np[3];
        np[0] = g[3]  - (g[0] * jx + g[1] * jy + g[2]  * jz);
        np[1] = g[7]  - (g[4] * jx + g[5] * jy + g[6]  * jz);
        np[2] = g[11] - (g[8] * jx + g[9] * jy + g[10] * jz);

        // permuted K position for this joint
        const int lkj = k >> 4;          // j / 16
        const int rr  = k & 15;
        const int qb  = 32 * (rr >> 1) + 8 * lkj + 4 * (rr & 1);
        #pragma unroll
        for (int i = 0; i < 3; ++i) {
            short4v o;
            o[0] = f2bf(g[i * 4 + 0]);
            o[1] = f2bf(g[i * 4 + 1]);
            o[2] = f2bf(g[i * 4 + 2]);
            o[3] = f2bf(np[i]);
            *(short4v*)&Bt[(size_t)(b * 3 + i) * KPAD + qb] = o;
        }
        if (k == 0) {   // zero K padding (joints 62,63 -> q 248..255)
            short4v z = {0, 0, 0, 0};
            #pragma unroll
            for (int i = 0; i < 3; ++i) {
                *(short4v*)&Bt[(size_t)(b * 3 + i) * KPAD + 248] = z;
                *(short4v*)&Bt[(size_t)(b * 3 + i) * KPAD + 252] = z;
            }
        }
    }
}

// ---------------------------------------------------------------------------
// Kernel 2: GEMM + epilogue — r21 structure (B in LDS swizzled, 3 waves/SIMD,
// deferred ping-pong stores, setprio) with the A-BUILD DELETED: A-frags are
// prefetched 16B loads from precomputed WH (permuted layout) — per visit the
// ~88-op VALU pack/gather (the largest term of the issue-cost stack) becomes
// 8 prefetched global loads. VGPR est ~116 <= 168 cap.
// Grid 768 (3 blocks/CU), 192 stripes x 16 y-groups.
// ---------------------------------------------------------------------------
__global__ __launch_bounds__(256, 3) void gemm_skin(
    const short* __restrict__ WH,     // (NV, KPAD) bf16, permuted K
    const short* __restrict__ Bt,     // (768, KPAD) bf16, permuted K
    const float* __restrict__ scale,  // (B,)
    const float* __restrict__ trans,  // (B*3,)
    float* __restrict__ out)          // (B, V, 3)
{
    __shared__ __align__(16) char ldsB[48 * 512];       // 24 KB B slab
    __shared__ __align__(16) float epi_all[4 * 1600];   // 25.6 KB epi (2 bufs/wave)

    const int tid  = threadIdx.x;
    const int wave = tid >> 6;
    const int lane = tid & 63;
    const int lrow = lane & 15;
    const int lk   = lane >> 4;
    const int yy    = blockIdx.x / 48;          // 0..15 (y-group)
    const int inner = blockIdx.x - yy * 48;     // 0..47
    const int s     = inner * 4 + wave;         // stripe 0..191
    const int start  = s * 4 + (s < 140 ? s : 140);
    const int ntiles = 4 + (s < 140 ? 1 : 0);   // 140*5 + 52*4 = 908
    const int b0 = yy * 16;
    float* epi0 = epi_all + wave * 1600;        // buf A: 16 regions x 50 f
    float* epi1 = epi0 + 800;                   // buf B

    // ---- stage B slab into LDS once (global_load_lds, both-sides swizzle)
    {
        const char* Bsrc = (const char*)(Bt + (size_t)yy * 48 * KPAD);
        #pragma unroll
        for (int cc = 0; cc < 6; ++cc) {
            const unsigned Lb = (unsigned)(wave * 6144 + cc * 1024);
            __builtin_amdgcn_global_load_lds(AS1(Bsrc + swz(Lb + lane * 16)),
                                             AS3(ldsB + Lb), 16, 0, 0);
        }
    }

    // ---- per-thread invariants (while DMA in flight)
    float sv[3], tv[3]; int eoff[3];
    #pragma unroll
    for (int nt = 0; nt < 3; ++nt) {
        const int n_loc = nt * 16 + lrow;
        const int bl = n_loc / 3, ii = n_loc - bl * 3;
        eoff[nt] = bl * 50 + ii;
        sv[nt] = scale[b0 + bl];
        tv[nt] = trans[(b0 + bl) * 3 + ii];
    }
    unsigned bofs[3], bxor[3];
    #pragma unroll
    for (int nt = 0; nt < 3; ++nt) {
        const unsigned brow = nt * 16 + lrow;
        bofs[nt] = brow * 512;
        bxor[nt] = (brow & 7u) << 4;
    }

    // deferred-store helper: flush tile tt from buffer ebuf
    auto do_store = [&](int tt, const float* ebuf) {
        const int m48 = (start + tt) * 48;
        const bool edge = (m48 + 48 > OUTF);
        #pragma unroll
        for (int it = 0; it < 6; ++it) {
            const int idx = it * 64 + lane;
            const int r = idx / 24, j = idx - r * 24;
            const floatx2 val = *(const floatx2*)&ebuf[r * 50 + 2 * j];
            const int pp = m48 + 2 * j;
            if (!edge || pp + 1 < OUTF)
                *(floatx2*)&out[(size_t)(b0 + r) * OUTF + pp] = val;
        }
    };

    // ---- prefetch tile 0's A-frags (8 x 16B from WH, lane-contiguous)
    short8v ac[8];
    {
        int vrow = start * 16 + lrow;
        if (vrow > NV - 1) vrow = NV - 1;
        const short* WHr = WH + (size_t)vrow * KPAD + lk * 8;
        #pragma unroll
        for (int k8 = 0; k8 < 8; ++k8)
            ac[k8] = *(const short8v*)(WHr + k8 * 32);
    }

    WAITVM0();
    __syncthreads();    // B slab resident; read-only hereafter

    for (int t = 0; t < ntiles; ++t) {
        float* ecur = (t & 1) ? epi1 : epi0;

        // ---- deferred store of tile t-1 (other buffer): drains under MFMA
        if (t > 0) do_store(t - 1, (t & 1) ? epi0 : epi1);

        // ---- issue prefetch for tile t+1's A-frags
        short8v an[8];
        if (t + 1 < ntiles) {
            int vr = (start + t + 1) * 16 + lrow;
            if (vr > NV - 1) vr = NV - 1;
            const short* WHr = WH + (size_t)vr * KPAD + lk * 8;
            #pragma unroll
            for (int k8 = 0; k8 < 8; ++k8)
                an[k8] = *(const short8v*)(WHr + k8 * 32);
        } else {
            #pragma unroll
            for (int k8 = 0; k8 < 8; ++k8)
                an[k8] = (short8v){0, 0, 0, 0, 0, 0, 0, 0};
        }

        // ---- MFMA: A from prefetched regs, B frags from LDS (swizzled)
        floatx4 acc[3];
        #pragma unroll
        for (int nt = 0; nt < 3; ++nt) acc[nt] = (floatx4){0.f, 0.f, 0.f, 0.f};
        __builtin_amdgcn_s_setprio(1);
        #pragma unroll
        for (int k8 = 0; k8 < 8; ++k8) {
            const unsigned cb = (unsigned)(k8 * 4 + lk) * 16;
            #pragma unroll
            for (int nt = 0; nt < 3; ++nt) {
                const short8v bf = *(const short8v*)(ldsB + bofs[nt] + (cb ^ bxor[nt]));
                acc[nt] = __builtin_amdgcn_mfma_f32_16x16x32_bf16(
                    ac[k8], bf, acc[nt], 0, 0, 0);
            }
        }
        __builtin_amdgcn_s_setprio(0);

        // ---- epilogue transpose into current buffer (stored next iter)
        #pragma unroll
        for (int nt = 0; nt < 3; ++nt) {
            #pragma unroll
            for (int r = 0; r < 4; ++r)
                ecur[eoff[nt] + (lk * 4 + r) * 3] =
                    fmaf(acc[nt][r], sv[nt], tv[nt]);
        }

        // ---- rotate prefetch
        #pragma unroll
        for (int k8 = 0; k8 < 8; ++k8) ac[k8] = an[k8];
    }

    // ---- epilogue: flush the final tile
    do_store(ntiles - 1, ((ntiles - 1) & 1) ? epi1 : epi0);
}

extern "C" void kernel_launch(void* const* d_in, const int* in_sizes, int n_in,
                              void* d_out, int out_size, void* d_ws, size_t ws_size,
                              hipStream_t stream)
{
    const float* thetas  = (const float*)d_in[0];
    const float* blc     = (const float*)d_in[1];
    const float* cbl     = (const float*)d_in[2];
    const float* trans   = (const float*)d_in[3];
    const float* scale   = (const float*)d_in[4];
    const float* vtempl  = (const float*)d_in[5];
    const float* tpose   = (const float*)d_in[6];
    const float* weights = (const float*)d_in[7];
    const int*   parents = (const int*)d_in[8];
    const int*   mapper  = (const int*)d_in[9];

    float* out  = (float*)d_out;
    float* Jout = out + (size_t)256 * NV * 3;

    short* Bt = (short*)d_ws;                    // 768*KPAD bf16 = 0.375 MB
    short* WH = Bt + (size_t)768 * KPAD;         // NV*KPAD bf16 = 7.44 MB

    prep_kernel<<<64 + WHBLK, 256, 0, stream>>>(
        thetas, blc, cbl, trans, scale, tpose, parents, mapper,
        weights, vtempl, Bt, WH, Jout);
    gemm_skin<<<768, 256, 0, stream>>>(WH, Bt, scale, trans, out);
}

// Round 23
// 24.945 us; speedup vs baseline: 2.4888x; 2.4888x over previous
//
#include <hip/hip_runtime.h>

#define NJ     62
#define NV     14522
#define NCORE  28
#define KPAD   256    // 62*4 = 248 padded to 256 (512 B per row)
#define OUTF   (NV * 3)        // 43566
#define MT     908             // m-tiles of 16 rows
#define NSTR   192             // stripes: 140 of 5 tiles, 52 of 4

typedef __attribute__((ext_vector_type(8))) short short8v;
typedef __attribute__((ext_vector_type(4))) short short4v;
typedef __attribute__((ext_vector_type(4))) float floatx4;
typedef __attribute__((ext_vector_type(2))) float floatx2;

#define AS1(p) ((const __attribute__((address_space(1))) void*)(p))
#define AS3(p) ((__attribute__((address_space(3))) void*)(p))

#define SCHED0() __builtin_amdgcn_sched_barrier(0)
#define WAITVM0() do { SCHED0(); asm volatile("s_waitcnt vmcnt(0)" ::: "memory"); SCHED0(); } while (0)

static __device__ inline short f2bf(float x) {
    unsigned u = __float_as_uint(x);
    unsigned r = (u + 0x7fffu + ((u >> 16) & 1u)) >> 16;
    return (short)r;
}

// pack 8 floats -> 8 bf16 (RNE) via v_cvt_pk_bf16_f32
static __device__ inline short8v pack8(float a0, float a1, float a2, float a3,
                                       float a4, float a5, float a6, float a7) {
    union { unsigned u[4]; short8v v; } p;
    asm("v_cvt_pk_bf16_f32 %0, %1, %2" : "=v"(p.u[0]) : "v"(a0), "v"(a1));
    asm("v_cvt_pk_bf16_f32 %0, %1, %2" : "=v"(p.u[1]) : "v"(a2), "v"(a3));
    asm("v_cvt_pk_bf16_f32 %0, %1, %2" : "=v"(p.u[2]) : "v"(a4), "v"(a5));
    asm("v_cvt_pk_bf16_f32 %0, %1, %2" : "=v"(p.u[3]) : "v"(a6), "v"(a7));
    return p.v;
}

// XOR swizzle over 512B rows: involution; global SOURCE at staging and LDS
// read addresses (both-sides rule). Proven in r6.
static __device__ inline unsigned swz(unsigned off) {
    return off ^ (((off >> 9) & 7u) << 4);
}

// ---------------------------------------------------------------------------
// Kernel 1: forward kinematics. 64 blocks x 256 thr; wave w = batch
// blockIdx*4+w. Writes Jout (fp32) and Bt (bf16) in the PERMUTED K layout:
//   joint j, comps m=0..3 at K-pos q = 32*((j%16)/2) + 8*(j/16) + 4*(j%2) + m
// (matches the gemm's per-lane-contiguous W mapping). Unchanged from r17.
// ---------------------------------------------------------------------------
__global__ __launch_bounds__(256) void fk_kernel(
    const float* __restrict__ thetas, const float* __restrict__ blc,
    const float* __restrict__ cbl, const float* __restrict__ trans,
    const float* __restrict__ scale, const float* __restrict__ tpose,
    const int* __restrict__ parents, const int* __restrict__ mapper,
    short* __restrict__ Bt, float* __restrict__ Jout)
{
    __shared__ float Asm[4][NJ][12];
    __shared__ float Gsm[4][NJ][12];

    const int w = threadIdx.x >> 6;
    const int b = blockIdx.x * 4 + w;
    const int k = threadIdx.x & 63;
    int p = 0;

    if (k < NJ) {
        p = parents[k];
        const float tz = thetas[(b * NJ + k) * 3 + 0];
        const float ty = thetas[(b * NJ + k) * 3 + 1];
        const float tx = thetas[(b * NJ + k) * 3 + 2];
        const float cx = cosf(tx), sx = sinf(tx);
        const float cy = cosf(ty), sy = sinf(ty);
        const float cz = cosf(tz), sz = sinf(tz);
        const float r00 = cz * cy;
        const float r01 = cz * sy * sx - sz * cx;
        const float r02 = sz * sx + cz * sy * cx;
        const float r10 = sz * cy;
        const float r11 = cz * cx + sz * sy * sx;
        const float r12 = sz * sy * cx - cz * sx;
        const float r20 = -sy;
        const float r21 = cy * sx;
        const float r22 = cy * cx;

        float f;
        const int m = mapper[k];
        if (k == 0)        f = 1.0f;
        else if (k == 1)   f = cbl[b];
        else if (m < 0)    f = 1.0f;
        else               f = 2.0f / (1.0f + expf(-blc[b * NCORE + m] * 0.2f));

        float ox, oy, oz;
        if (k == 0) {
            ox = tpose[0]; oy = tpose[1]; oz = tpose[2];
        } else {
            ox = (tpose[k * 3 + 0] - tpose[p * 3 + 0]) * f;
            oy = (tpose[k * 3 + 1] - tpose[p * 3 + 1]) * f;
            oz = (tpose[k * 3 + 2] - tpose[p * 3 + 2]) * f;
        }
        Asm[w][k][0] = r00; Asm[w][k][1] = r01; Asm[w][k][2]  = r02; Asm[w][k][3]  = ox;
        Asm[w][k][4] = r10; Asm[w][k][5] = r11; Asm[w][k][6]  = r12; Asm[w][k][7]  = oy;
        Asm[w][k][8] = r20; Asm[w][k][9] = r21; Asm[w][k][10] = r22; Asm[w][k][11] = oz;
    }
    __syncthreads();

    if (k == 0) {
        #pragma unroll
        for (int j = 0; j < 12; ++j) Gsm[w][0][j] = Asm[w][0][j];
    }
    __syncthreads();

    const int depth = (k < NJ) ? (31 - __clz((unsigned)(k + 1))) : 99;
    for (int d = 1; d <= 5; ++d) {
        if (depth == d) {
            float gp[12], a[12], g[12];
            #pragma unroll
            for (int j = 0; j < 12; ++j) { gp[j] = Gsm[w][p][j]; a[j] = Asm[w][k][j]; }
            #pragma unroll
            for (int i = 0; i < 3; ++i) {
                #pragma unroll
                for (int j = 0; j < 4; ++j) {
                    float s = (j == 3) ? gp[i * 4 + 3] : 0.0f;
                    s = fmaf(gp[i * 4 + 0], a[0 * 4 + j], s);
                    s = fmaf(gp[i * 4 + 1], a[1 * 4 + j], s);
                    s = fmaf(gp[i * 4 + 2], a[2 * 4 + j], s);
                    g[i * 4 + j] = s;
                }
            }
            #pragma unroll
            for (int j = 0; j < 12; ++j) Gsm[w][k][j] = g[j];
        }
        __syncthreads();
    }

    if (k < NJ) {
        float g[12];
        #pragma unroll
        for (int j = 0; j < 12; ++j) g[j] = Gsm[w][k][j];
        const float jx = tpose[k * 3 + 0];
        const float jy = tpose[k * 3 + 1];
        const float jz = tpose[k * 3 + 2];
        const float s  = scale[b];
        Jout[(b * NJ + k) * 3 + 0] = fmaf(g[3],  s, trans[b * 3 + 0]);
        Jout[(b * NJ + k) * 3 + 1] = fmaf(g[7],  s, trans[b * 3 + 1]);
        Jout[(b * NJ + k) * 3 + 2] = fmaf(g[11], s, trans[b * 3 + 2]);
        float np[3];
        np[0] = g[3]  - (g[0] * jx + g[1] * jy + g[2]  * jz);
        np[1] = g[7]  - (g[4] * jx + g[5] * jy + g[6]  * jz);
        np[2] = g[11] - (g[8] * jx + g[9] * jy + g[10] * jz);

        // permuted K position for this joint
        const int lkj = k >> 4;          // j / 16
        const int rr  = k & 15;
        const int qb  = 32 * (rr >> 1) + 8 * lkj + 4 * (rr & 1);
        #pragma unroll
        for (int i = 0; i < 3; ++i) {
            short4v o;
            o[0] = f2bf(g[i * 4 + 0]);
            o[1] = f2bf(g[i * 4 + 1]);
            o[2] = f2bf(g[i * 4 + 2]);
            o[3] = f2bf(np[i]);
            *(short4v*)&Bt[(size_t)(b * 3 + i) * KPAD + qb] = o;
        }
        if (k == 0) {   // zero K padding (joints 62,63 -> q 248..255)
            short4v z = {0, 0, 0, 0};
            #pragma unroll
            for (int i = 0; i < 3; ++i) {
                *(short4v*)&Bt[(size_t)(b * 3 + i) * KPAD + 248] = z;
                *(short4v*)&Bt[(size_t)(b * 3 + i) * KPAD + 252] = z;
            }
        }
    }
}

// ---------------------------------------------------------------------------
// Kernel 2: GEMM + epilogue — the r21 best (24.95us), restored verbatim:
//  - permuted K layout: each lane's 16 W weights contiguous (4 float4),
//    prefetched one tile ahead (chain head off the critical path).
//  - A frags built inline per k8 (32 VGPR loop-carried state: under the
//    compiler's spill cliff — r18/r22 showed >=64 VGPR arrays get spilled).
//  - B slab in LDS (24 KB, staged once, both-sides XOR swizzle).
//  - deferred ping-pong stores: tile t's stores issue at top of t+1, so the
//    epi ds_write->ds_read->store tail drains under the next tile's MFMA.
//  - s_setprio(1) around the MFMA cluster (neutral but harmless).
// Grid 768 (3 blocks/CU, 3 waves/SIMD); LDS = 24KB B + 25.6KB epi = 49.7KB.
// ---------------------------------------------------------------------------
__global__ __launch_bounds__(256, 3) void gemm_skin(
    const float* __restrict__ W,      // (V, 62) fp32
    const float* __restrict__ vt,     // (V, 3)  fp32
    const short* __restrict__ Bt,     // (768, KPAD) bf16, permuted K
    const float* __restrict__ scale,  // (B,)
    const float* __restrict__ trans,  // (B*3,)
    float* __restrict__ out)          // (B, V, 3)
{
    __shared__ __align__(16) char ldsB[48 * 512];       // 24 KB B slab
    __shared__ __align__(16) float epi_all[4 * 1600];   // 25.6 KB epi (2 bufs/wave)

    const int tid  = threadIdx.x;
    const int wave = tid >> 6;
    const int lane = tid & 63;
    const int lrow = lane & 15;
    const int lk   = lane >> 4;
    const int yy    = blockIdx.x / 48;          // 0..15 (y-group)
    const int inner = blockIdx.x - yy * 48;     // 0..47
    const int s     = inner * 4 + wave;         // stripe 0..191
    const int start  = s * 4 + (s < 140 ? s : 140);
    const int ntiles = 4 + (s < 140 ? 1 : 0);   // 140*5 + 52*4 = 908
    const int b0 = yy * 16;
    float* epi0 = epi_all + wave * 1600;        // buf A: 16 regions x 50 f
    float* epi1 = epi0 + 800;                   // buf B

    // ---- stage B slab into LDS once (global_load_lds, both-sides swizzle)
    {
        const char* Bsrc = (const char*)(Bt + (size_t)yy * 48 * KPAD);
        #pragma unroll
        for (int cc = 0; cc < 6; ++cc) {
            const unsigned Lb = (unsigned)(wave * 6144 + cc * 1024);
            __builtin_amdgcn_global_load_lds(AS1(Bsrc + swz(Lb + lane * 16)),
                                             AS3(ldsB + Lb), 16, 0, 0);
        }
    }

    // ---- per-thread invariants (while DMA in flight)
    float sv[3], tv[3]; int eoff[3];
    #pragma unroll
    for (int nt = 0; nt < 3; ++nt) {
        const int n_loc = nt * 16 + lrow;
        const int bl = n_loc / 3, ii = n_loc - bl * 3;
        eoff[nt] = bl * 50 + ii;
        sv[nt] = scale[b0 + bl];
        tv[nt] = trans[(b0 + bl) * 3 + ii];
    }
    unsigned bofs[3], bxor[3];
    #pragma unroll
    for (int nt = 0; nt < 3; ++nt) {
        const unsigned brow = nt * 16 + lrow;
        bofs[nt] = brow * 512;
        bxor[nt] = (brow & 7u) << 4;
    }

    // deferred-store helper: flush tile tt from buffer ebuf
    auto do_store = [&](int tt, const float* ebuf) {
        const int m48 = (start + tt) * 48;
        const bool edge = (m48 + 48 > OUTF);
        #pragma unroll
        for (int it = 0; it < 6; ++it) {
            const int idx = it * 64 + lane;
            const int r = idx / 24, j = idx - r * 24;
            const floatx2 val = *(const floatx2*)&ebuf[r * 50 + 2 * j];
            const int pp = m48 + 2 * j;
            if (!edge || pp + 1 < OUTF)
                *(floatx2*)&out[(size_t)(b0 + r) * OUTF + pp] = val;
        }
    };

    // ---- prefetch tile 0's W (4 coalesced float4: 16 contiguous weights
    //      at W[row] + 16*lk) and vt row
    floatx4 wc[4]; float hcx, hcy, hcz;
    {
        int vrow = start * 16 + lrow;
        if (vrow > NV - 1) vrow = NV - 1;
        const float* Wb = W + (size_t)vrow * NJ + lk * 16;
        wc[0] = *(const floatx4*)(Wb + 0);
        wc[1] = *(const floatx4*)(Wb + 4);
        wc[2] = *(const floatx4*)(Wb + 8);
        wc[3] = *(const floatx4*)(Wb + 12);
        hcx = vt[vrow * 3 + 0]; hcy = vt[vrow * 3 + 1]; hcz = vt[vrow * 3 + 2];
    }

    WAITVM0();
    __syncthreads();    // B slab resident; read-only hereafter

    for (int t = 0; t < ntiles; ++t) {
        float* ecur = (t & 1) ? epi1 : epi0;

        // ---- deferred store of tile t-1 (other buffer): its LDS data was
        //      written last iteration; stores drain under THIS tile's MFMA.
        if (t > 0) do_store(t - 1, (t & 1) ? epi0 : epi1);

        // ---- issue prefetch for tile t+1 (latency hidden under MFMA)
        floatx4 wn[4]; float hnx = 0.f, hny = 0.f, hnz = 0.f;
        if (t + 1 < ntiles) {
            int vr = (start + t + 1) * 16 + lrow;
            if (vr > NV - 1) vr = NV - 1;
            const float* Wb = W + (size_t)vr * NJ + lk * 16;
            wn[0] = *(const floatx4*)(Wb + 0);
            wn[1] = *(const floatx4*)(Wb + 4);
            wn[2] = *(const floatx4*)(Wb + 8);
            wn[3] = *(const floatx4*)(Wb + 12);
            hnx = vt[vr * 3 + 0]; hny = vt[vr * 3 + 1]; hnz = vt[vr * 3 + 2];
        } else {
            wn[0] = wn[1] = wn[2] = wn[3] = (floatx4){0.f, 0.f, 0.f, 0.f};
        }

        // ---- MFMA: A frag built inline per k8 from contiguous weights;
        //      B frags from LDS (swizzled ds_read_b128).
        floatx4 acc[3];
        #pragma unroll
        for (int nt = 0; nt < 3; ++nt) acc[nt] = (floatx4){0.f, 0.f, 0.f, 0.f};
        __builtin_amdgcn_s_setprio(1);
        #pragma unroll
        for (int k8 = 0; k8 < 8; ++k8) {
            // joints 16*lk + 2*k8, +1  ->  wc[k8/2][2*(k8%2)], [..+1]
            float w0 = wc[k8 >> 1][2 * (k8 & 1)];
            float w1 = wc[k8 >> 1][2 * (k8 & 1) + 1];
            if (lk == 3 && k8 == 7) { w0 = 0.f; w1 = 0.f; }   // joints 62,63
            const short8v a = pack8(w0 * hcx, w0 * hcy, w0 * hcz, w0,
                                    w1 * hcx, w1 * hcy, w1 * hcz, w1);
            const unsigned cb = (unsigned)(k8 * 4 + lk) * 16;
            #pragma unroll
            for (int nt = 0; nt < 3; ++nt) {
                const short8v bf = *(const short8v*)(ldsB + bofs[nt] + (cb ^ bxor[nt]));
                acc[nt] = __builtin_amdgcn_mfma_f32_16x16x32_bf16(
                    a, bf, acc[nt], 0, 0, 0);
            }
        }
        __builtin_amdgcn_s_setprio(0);

        // ---- epilogue transpose into current buffer (stored next iter)
        #pragma unroll
        for (int nt = 0; nt < 3; ++nt) {
            #pragma unroll
            for (int r = 0; r < 4; ++r)
                ecur[eoff[nt] + (lk * 4 + r) * 3] =
                    fmaf(acc[nt][r], sv[nt], tv[nt]);
        }

        // ---- rotate prefetch
        wc[0] = wn[0]; wc[1] = wn[1]; wc[2] = wn[2]; wc[3] = wn[3];
        hcx = hnx; hcy = hny; hcz = hnz;
    }

    // ---- epilogue: flush the final tile
    do_store(ntiles - 1, ((ntiles - 1) & 1) ? epi1 : epi0);
}

extern "C" void kernel_launch(void* const* d_in, const int* in_sizes, int n_in,
                              void* d_out, int out_size, void* d_ws, size_t ws_size,
                              hipStream_t stream)
{
    const float* thetas  = (const float*)d_in[0];
    const float* blc     = (const float*)d_in[1];
    const float* cbl     = (const float*)d_in[2];
    const float* trans   = (const float*)d_in[3];
    const float* scale   = (const float*)d_in[4];
    const float* vtempl  = (const float*)d_in[5];
    const float* tpose   = (const float*)d_in[6];
    const float* weights = (const float*)d_in[7];
    const int*   parents = (const int*)d_in[8];
    const int*   mapper  = (const int*)d_in[9];

    float* out  = (float*)d_out;
    float* Jout = out + (size_t)256 * NV * 3;

    short* Bt = (short*)d_ws;                    // 768*KPAD bf16 = 0.39 MB

    fk_kernel<<<64, 256, 0, stream>>>(thetas, blc, cbl, trans, scale, tpose,
                                      parents, mapper, Bt, Jout);
    gemm_skin<<<768, 256, 0, stream>>>(weights, vtempl, Bt, scale, trans, out);
}